// Round 1
// baseline (133.022 us; speedup 1.0000x reference)
//
#include <hip/hip_runtime.h>
#include <math.h>

#define DEPTH 15
#define N_LEAVES (1 << DEPTH)        // 32768
#define N_NODES (2 * N_LEAVES - 1)   // 65535
#define FDIM 256
#define CDIM 2
#define ROWF (FDIM * CDIM)           // 512 floats per node row
#define LPW 8                        // leaves per wave
#define MIN_DIST 1e-7f

// Apply one delta-node row to leaves [S, S+N) of this wave's 8-leaf chunk.
// All indices compile-time -> acc/xf stay in registers.
template <int S, int N, bool OWNED>
__device__ __forceinline__ void apply_node(int node, int lane,
                                           const float* __restrict__ deltas,
                                           const float* __restrict__ bl,
                                           const float4 (&xf)[LPW],
                                           float (&acc0)[LPW],
                                           float (&acc1)[LPW],
                                           float& reg) {
    const float* dpf = deltas + (size_t)node * ROWF + lane * 8;
    float4 d0 = *(const float4*)(dpf);      // (f0,c0)(f0,c1)(f1,c0)(f1,c1)
    float4 d1 = *(const float4*)(dpf + 4);  // (f2,c0)(f2,c1)(f3,c0)(f3,c1)
#pragma unroll
    for (int i = S; i < S + N; ++i) {
        acc0[i] += xf[i].x * d0.x + xf[i].y * d0.z + xf[i].z * d1.x + xf[i].w * d1.z;
        acc1[i] += xf[i].x * d0.y + xf[i].y * d0.w + xf[i].z * d1.y + xf[i].w * d1.w;
    }
    if (OWNED) {
        float s8 = fabsf(d0.x) + fabsf(d0.y) + fabsf(d0.z) + fabsf(d0.w)
                 + fabsf(d1.x) + fabsf(d1.y) + fabsf(d1.z) + fabsf(d1.w);
        float dist = fmaxf(bl[node - 1], MIN_DIST);  // owned nodes are never root
        reg += s8 / dist;
    }
}

__global__ __launch_bounds__(256) void tree_main(const float* __restrict__ x,
                                                 const float* __restrict__ deltas,
                                                 const float* __restrict__ bl,
                                                 float* __restrict__ out) {
    int tid = blockIdx.x * blockDim.x + threadIdx.x;
    int wave = tid >> 6;         // 0 .. 4095
    int lane = tid & 63;
    int leaf0 = wave * LPW;

    // x fragments: lane owns features [4*lane, 4*lane+4) for each of 8 leaves
    float4 xf[LPW];
#pragma unroll
    for (int i = 0; i < LPW; ++i)
        xf[i] = *(const float4*)(x + (size_t)(leaf0 + i) * FDIM + lane * 4);

    float acc0[LPW], acc1[LPW];
#pragma unroll
    for (int i = 0; i < LPW; ++i) { acc0[i] = 0.f; acc1[i] = 0.f; }

    float reg = 0.f;

    // Levels 0..11: one shared ancestor covers all 8 leaves; NOT owned (covers >8 leaves)
#pragma unroll
    for (int l = 0; l <= 11; ++l) {
        int node = ((1 << l) - 1) + (leaf0 >> (DEPTH - l));
        apply_node<0, 8, false>(node, lane, deltas, bl, xf, acc0, acc1, reg);
    }
    // Level 12: one node covering exactly our 8 leaves -> owned
    {
        int node = ((1 << 12) - 1) + (leaf0 >> 3);
        apply_node<0, 8, true>(node, lane, deltas, bl, xf, acc0, acc1, reg);
    }
    // Level 13: 2 nodes x 4 leaves, owned
    {
        int base = ((1 << 13) - 1) + (leaf0 >> 2);
        apply_node<0, 4, true>(base + 0, lane, deltas, bl, xf, acc0, acc1, reg);
        apply_node<4, 4, true>(base + 1, lane, deltas, bl, xf, acc0, acc1, reg);
    }
    // Level 14: 4 nodes x 2 leaves, owned
    {
        int base = ((1 << 14) - 1) + (leaf0 >> 1);
        apply_node<0, 2, true>(base + 0, lane, deltas, bl, xf, acc0, acc1, reg);
        apply_node<2, 2, true>(base + 1, lane, deltas, bl, xf, acc0, acc1, reg);
        apply_node<4, 2, true>(base + 2, lane, deltas, bl, xf, acc0, acc1, reg);
        apply_node<6, 2, true>(base + 3, lane, deltas, bl, xf, acc0, acc1, reg);
    }
    // Level 15: 8 nodes x 1 leaf, owned
    {
        int base = ((1 << 15) - 1) + leaf0;
        apply_node<0, 1, true>(base + 0, lane, deltas, bl, xf, acc0, acc1, reg);
        apply_node<1, 1, true>(base + 1, lane, deltas, bl, xf, acc0, acc1, reg);
        apply_node<2, 1, true>(base + 2, lane, deltas, bl, xf, acc0, acc1, reg);
        apply_node<3, 1, true>(base + 3, lane, deltas, bl, xf, acc0, acc1, reg);
        apply_node<4, 1, true>(base + 4, lane, deltas, bl, xf, acc0, acc1, reg);
        apply_node<5, 1, true>(base + 5, lane, deltas, bl, xf, acc0, acc1, reg);
        apply_node<6, 1, true>(base + 6, lane, deltas, bl, xf, acc0, acc1, reg);
        apply_node<7, 1, true>(base + 7, lane, deltas, bl, xf, acc0, acc1, reg);
    }

    // Butterfly-reduce logits across the wave (every lane ends with the total)
#pragma unroll
    for (int i = 0; i < LPW; ++i) {
#pragma unroll
        for (int m = 1; m < 64; m <<= 1) {
            acc0[i] += __shfl_xor(acc0[i], m, 64);
            acc1[i] += __shfl_xor(acc1[i], m, 64);
        }
    }

    // Softmax + store: lane i writes leaf i (static unroll, no dynamic reg indexing)
#pragma unroll
    for (int i = 0; i < LPW; ++i) {
        if (lane == i) {
            float m = fmaxf(acc0[i], acc1[i]);
            float e0 = __expf(acc0[i] - m);
            float e1 = __expf(acc1[i] - m);
            float inv = 1.f / (e0 + e1);
            *(float2*)(out + (size_t)(leaf0 + i) * CDIM) = make_float2(e0 * inv, e1 * inv);
        }
    }

    // Regularizer partial for owned nodes (levels 12..15)
#pragma unroll
    for (int m = 1; m < 64; m <<= 1) reg += __shfl_xor(reg, m, 64);
    if (lane == 0) atomicAdd(out + (size_t)N_LEAVES * CDIM, reg);
}

// Nodes 0 .. 4094 (levels 0..11): root squared-sum + |.|/dist for the rest.
__global__ __launch_bounds__(256) void tree_reg(const float* __restrict__ deltas,
                                                const float* __restrict__ bl,
                                                float* __restrict__ out) {
    int tid = blockIdx.x * blockDim.x + threadIdx.x;
    int wave = tid >> 6;
    int lane = tid & 63;
    const int NAUX = (1 << 12) - 1;  // 4095 nodes: 0..4094
    if (wave >= NAUX) return;
    int node = wave;

    const float* dpf = deltas + (size_t)node * ROWF + lane * 8;
    float4 d0 = *(const float4*)(dpf);
    float4 d1 = *(const float4*)(dpf + 4);

    float v;
    if (node == 0) {
        v = d0.x * d0.x + d0.y * d0.y + d0.z * d0.z + d0.w * d0.w
          + d1.x * d1.x + d1.y * d1.y + d1.z * d1.z + d1.w * d1.w;
    } else {
        float s8 = fabsf(d0.x) + fabsf(d0.y) + fabsf(d0.z) + fabsf(d0.w)
                 + fabsf(d1.x) + fabsf(d1.y) + fabsf(d1.z) + fabsf(d1.w);
        v = s8 / fmaxf(bl[node - 1], MIN_DIST);
    }
#pragma unroll
    for (int m = 1; m < 64; m <<= 1) v += __shfl_xor(v, m, 64);
    if (lane == 0) atomicAdd(out + (size_t)N_LEAVES * CDIM, v);
}

extern "C" void kernel_launch(void* const* d_in, const int* in_sizes, int n_in,
                              void* d_out, int out_size, void* d_ws, size_t ws_size,
                              hipStream_t stream) {
    const float* x      = (const float*)d_in[0];
    const float* deltas = (const float*)d_in[1];
    const float* bl     = (const float*)d_in[2];
    float* out = (float*)d_out;

    // zero the scalar accumulator (graph-capture-safe async memset)
    hipMemsetAsync(out + (size_t)N_LEAVES * CDIM, 0, sizeof(float), stream);

    // main: 4096 waves x 8 leaves = 32768 leaves; 4 waves/block -> 1024 blocks
    tree_main<<<1024, 256, 0, stream>>>(x, deltas, bl, out);
    // aux regularizer: 4095 waves, 4 waves/block -> 1024 blocks
    tree_reg<<<1024, 256, 0, stream>>>(deltas, bl, out);
}